// Round 4
// baseline (431.304 us; speedup 1.0000x reference)
//
#include <hip/hip_runtime.h>

typedef unsigned short ushort_t;
typedef unsigned int uint_t;

using short8 = __attribute__((ext_vector_type(8))) short;
using f32x4  = __attribute__((ext_vector_type(4))) float;

#define N_BATCH   64
#define C_MID     256
#define H_OUT     28
#define W_OUT     28
#define SPATIAL   (H_OUT*W_OUT)
#define OUT_ELEMS (N_BATCH*C_MID*SPATIAL)   // 12,845,056

// histogram: 2048 bins over [-16,16), width 1/64
#define NBINS 2048
#define BIN_LO (-16.0f)
#define BIN_INV 64.0f
#define BIN_W  0.015625f

// padded channels-last geometry (u16 element units)
#define XT_ROW   (57*128)        // 7296
#define XT_IMG   (57*57*128)     // 415872
#define O1_ROW   (30*256)        // 7680
#define O1_IMG   (30*30*256)     // 230400

// counted waits + raw barrier (memory clobber pins LDS reads/writes ordering)
#define WAITVM(n) asm volatile("s_waitcnt vmcnt(" #n ")" ::: "memory")
#define BARRIER() asm volatile("s_barrier" ::: "memory")

__device__ __forceinline__ ushort_t f2bf(float f) {
    uint_t u = __float_as_uint(f);
    u += 0x7FFFu + ((u >> 16) & 1u);
    return (ushort_t)(u >> 16);
}

__device__ __forceinline__ void gll16(const ushort_t* g, void* l) {
    __builtin_amdgcn_global_load_lds(
        (const __attribute__((address_space(1))) unsigned int*)g,
        (__attribute__((address_space(3))) unsigned int*)l, 16, 0, 0);
}

// ---------------------------------------------------------------------------
// Merged: zero borders of xT/o1T (blocks x<87) + weight transform (x>=87).
// ---------------------------------------------------------------------------
__global__ __launch_bounds__(256) void zwtrans(
    uint_t* __restrict__ xT32, uint_t* __restrict__ o1T32,
    const float* __restrict__ w1, const float* __restrict__ w2,
    const float* __restrict__ wid, ushort_t* __restrict__ wT1,
    ushort_t* __restrict__ wT2)
{
    const int bxx = blockIdx.x, y = blockIdx.y, tid = threadIdx.x;
    if (bxx < 87) {
        int i = bxx * 256 + tid;
        int n = y;
        if (i >= 22080) return;
        if (i < 7232) {
            uint_t* base = xT32 + (size_t)n * (XT_IMG / 2);
            if (i < 3648) base[i] = 0;                              // row 0
            else { int j = i - 3648; int r = (j >> 6) + 1;          // col 0
                   base[r * (XT_ROW / 2) + (j & 63)] = 0; }
        } else {
            int k = i - 7232;
            uint_t* base = o1T32 + (size_t)n * (O1_IMG / 2);
            if (k < 3840) base[k] = 0;                              // row 0
            else if (k < 7680) base[29 * (O1_ROW / 2) + (k - 3840)] = 0;
            else if (k < 11264) { int j = k - 7680; int r = (j >> 7) + 1;
                   base[r * (O1_ROW / 2) + (j & 127)] = 0; }        // col 0
            else { int j = k - 11264; int r = (j >> 7) + 1;
                   base[r * (O1_ROW / 2) + 29 * 128 + (j & 127)] = 0; }
        }
    } else {
        int idx = ((bxx - 87) * 64 + y) * 256 + tid;   // 0..622591
        if (idx < 256 * 1152) {
            int co = idx / 1152, k = idx % 1152;
            int g = k >> 7, ci = k & 127;
            wT1[idx] = f2bf(w1[(co * 128 + ci) * 9 + g]);
        }
        if (idx < 256 * 2432) {
            int co = idx / 2432, k = idx % 2432;
            float v;
            if (k < 2304) { int g = k >> 8, ci = k & 255; v = w2[(co * 256 + ci) * 9 + g]; }
            else          { v = wid[co * 128 + (k - 2304)]; }
            wT2[idx] = f2bf(v);
        }
    }
}

// ---------------------------------------------------------------------------
// x transform: NCHW f32 -> padded channels-last bf16 xT[n][1+ih][1+iw][ci]
// ---------------------------------------------------------------------------
__global__ __launch_bounds__(256) void xtrans(
    const float* __restrict__ x, ushort_t* __restrict__ xT)
{
    __shared__ ushort_t t[224 * 130];
    const int tid = threadIdx.x;
    const int g = blockIdx.x, n = blockIdx.y;
    const float* xs = x + ((size_t)n * 128) * 3136 + g * 4 * 56;

    for (int it = 0; it < 112; ++it) {
        int f = it * 256 + tid;
        int ci = f / 224, rem = f % 224;
        t[rem * 130 + ci] = f2bf(xs[ci * 3136 + rem]);
    }
    __syncthreads();
    ushort_t* xo = xT + (size_t)n * XT_IMG + (g * 4 + 1) * XT_ROW + 128;
    for (int it = 0; it < 56; ++it) {
        int f = it * 256 + tid;
        int pos = f >> 6, c2 = f & 63;
        int r = pos / 56, iw = pos % 56;
        uint_t v = *(const uint_t*)&t[pos * 130 + c2 * 2];
        *(uint_t*)(xo + r * XT_ROW + iw * 128 + c2 * 2) = v;
    }
}

// ---------------------------------------------------------------------------
// conv1, R4: 512 threads (8 waves), same 448-block grid. Each wave owns a
// 32-co x 112-pos tile -> acc[2][7] (56 VGPR). A staging is WAVE-PRIVATE
// (2 insts/wave covering its own 32 co x 32 ci), double-buffered, counted
// vmcnt(2) per tap, no per-tap barrier (R1's proven pattern). Shared B
// patch: 36 insts spread over waves (waves 0-3: 5, waves 4-7: 4), published
// by the per-chunk WAITVM(0)+BARRIER. LDS 32+36=68KB -> 2 blocks/CU
// -> 16 waves/CU (4/SIMD), 2x the R1 occupancy.
// ---------------------------------------------------------------------------
__global__ __launch_bounds__(512, 4) void conv1_mfma(
    const ushort_t* __restrict__ xT, const ushort_t* __restrict__ wT1,
    ushort_t* __restrict__ o1T, ushort_t* __restrict__ bh)
{
    const int bx = blockIdx.x;           // n*7 + rg
    const int tid = threadIdx.x;
    const int wv = tid >> 6, lane = tid & 63;
    const int ln = lane & 15, quad = lane >> 4;
    const int n = bx / 7, rg = bx % 7, r0 = rg * 4;

    __shared__ short8 Ald[2 * 1024];     // 32 KB [buf][wv 8][k8 4][cor 32]
    __shared__ short8 Bp[2304];          // 36 KB [k8 4][dr 9][j 57] (513/plane)

    f32x4 acc[2][7];
    #pragma unroll
    for (int a = 0; a < 2; ++a)
        #pragma unroll
        for (int b = 0; b < 7; ++b) acc[a][b] = (f32x4){0.f, 0.f, 0.f, 0.f};

    int drb[7], cl0[7];
    #pragma unroll
    for (int b = 0; b < 7; ++b) {
        int p = b * 16 + ln;
        drb[b] = 2 * (p / 28);           // + kh at use
        cl0[b] = p % 28;
    }

    // B patch staging: 36 insts; wave wv does insts it = i*8+wv (it<36)
    uint_t poff[5];
    #pragma unroll
    for (int i = 0; i < 5; ++i) {
        int it = i * 8 + wv;
        int slot = it * 64 + lane;
        int s2 = min(slot, 2051);
        int k8 = s2 / 513;
        int rem = s2 - k8 * 513;
        int dr = rem / 57, j = rem - dr * 57;
        int col = (j < 29) ? (2 * j) : (2 * (j - 29) + 1);
        poff[i] = (uint_t)((2 * r0 + dr) * XT_ROW + col * 128 + k8 * 8);
    }
    // wave-private A source: lane-element mapping elem = jj*64+lane
    const ushort_t* asrc[2];
    #pragma unroll
    for (int jj = 0; jj < 2; ++jj) {
        int elem = jj * 64 + lane;
        int k8e = elem >> 5, cor = elem & 31;
        asrc[jj] = wT1 + (size_t)(wv * 32 + cor) * 1152 + k8e * 8;
    }

    const ushort_t* xTimg = xT + (size_t)n * XT_IMG;

    auto stageA = [&](int tap, int c, int buf) {     // 2 insts, wave-private 2KB
        #pragma unroll
        for (int jj = 0; jj < 2; ++jj)
            gll16(asrc[jj] + tap * 128 + c * 32,
                  (char*)Ald + buf * 16384 + wv * 2048 + jj * 1024);
    };

    for (int c = 0; c < 4; ++c) {
        BARRIER();                       // all waves done reading Bp (prev chunk)
        #pragma unroll
        for (int i = 0; i < 5; ++i) {
            int it = i * 8 + wv;
            if (it < 36)
                gll16(xTimg + poff[i] + c * 32, (char*)Bp + it * 1024);
        }
        if (c == 0) stageA(0, 0, 0);
        WAITVM(0);                       // own B+A shares arrived
        BARRIER();                       // everyone's B arrived

        for (int t = 0; t < 9; ++t) {
            const int st = c * 9 + t;
            const int buf = st & 1;
            if (t < 8)      stageA(t + 1, c, buf ^ 1);
            else if (c < 3) stageA(0, c + 1, buf ^ 1);
            if (c == 3 && t == 8) { WAITVM(0); } else { WAITVM(2); }
            const int kh = t / 3, kw = t - kh * 3;
            short8 af[2], bf[7];
            #pragma unroll
            for (int a = 0; a < 2; ++a)
                af[a] = Ald[buf * 1024 + wv * 128 + quad * 32 + a * 16 + ln];
            #pragma unroll
            for (int b = 0; b < 7; ++b) {
                int dr = drb[b] + kh;
                int j = (kw == 1) ? (29 + cl0[b]) : (cl0[b] + (kw >> 1));
                bf[b] = Bp[quad * 513 + dr * 57 + j];
            }
            __builtin_amdgcn_s_setprio(1);
            #pragma unroll
            for (int a = 0; a < 2; ++a)
                #pragma unroll
                for (int b = 0; b < 7; ++b)
                    acc[a][b] = __builtin_amdgcn_mfma_f32_16x16x32_bf16(
                        af[a], bf[b], acc[a][b], 0, 0, 0);
            __builtin_amdgcn_s_setprio(0);
        }
    }

    // epilogue: hist overlaid on Ald; clamp -> bf16 o1T (padded channels-last)
    __syncthreads();
    uint_t* hist = (uint_t*)Ald;
    for (int i = tid; i < NBINS; i += 512) hist[i] = 0;
    __syncthreads();

    ushort_t* oimg = o1T + (size_t)n * O1_IMG;
    #pragma unroll
    for (int a = 0; a < 2; ++a) {
        int co = wv * 32 + a * 16 + quad * 4;
        #pragma unroll
        for (int b = 0; b < 7; ++b) {
            int p = b * 16 + ln;
            int h = r0 + p / 28, w = p % 28;
            ushort_t pk[4];
            #pragma unroll
            for (int r = 0; r < 4; ++r) {
                float v = acc[a][b][r];
                int bin = (int)((v - BIN_LO) * BIN_INV);
                bin = min(max(bin, 0), NBINS - 1);
                atomicAdd(&hist[bin], 1u);
                pk[r] = f2bf(fminf(fmaxf(v, 0.f), 1.f));
            }
            uint2 u; u.x = (uint_t)pk[0] | ((uint_t)pk[1] << 16);
            u.y = (uint_t)pk[2] | ((uint_t)pk[3] << 16);
            *(uint2*)(oimg + ((h + 1) * 30 + (w + 1)) * 256 + co) = u;
        }
    }

    __syncthreads();
    size_t blin = (size_t)bx * NBINS;
    for (int i = tid; i < NBINS; i += 512) bh[blin + i] = (ushort_t)hist[i];
}

// ---------------------------------------------------------------------------
// conv2 + fused identity, R4: 512 threads (8 waves), 4-row groups, grid 448
// (by merged -> B staged ONCE per tile). Sync = R1's proven per-step barrier
// + lead-1 A into a TRIPLE buffer + counted vmcnt. Per-step issues (per
// wave): A(s+1)[2]; t==1 adds B[2] (or I[1] at h==7). Waits: t in {1,2}:
// WAITVM(4) (h<7) / WAITVM(3) (h==7); else WAITVM(2) -- each wave retires
// its own share of A(s) before the barrier, so the barrier publishes the
// cooperative buffers (R1's publish rule). Write safety: lead-1 + triple-A
// (buf (s+1)%3 last read at s-2, all readers past barrier s-1); B buf
// (h+1)&1 last read in chunk h-1, all readers past barrier (h,0).
// LDS: A 3x16KB + B 2x12KB = 72KB -> 2 blocks/CU -> 16 waves/CU.
// All 28 rows valid (28 = 7x4): no clamping anywhere.
// ---------------------------------------------------------------------------
__global__ __launch_bounds__(512, 4) void conv2_mfma(
    const ushort_t* __restrict__ o1T, const ushort_t* __restrict__ xT,
    const ushort_t* __restrict__ wT2, float* __restrict__ fout,
    ushort_t* __restrict__ bh)
{
    const int bx = blockIdx.x;           // n*7 + rg
    const int tid = threadIdx.x;
    const int wv = tid >> 6, lane = tid & 63;
    const int ln = lane & 15, quad = lane >> 4;
    const int n = bx / 7, rg = bx % 7, r0 = rg * 4;

    __shared__ short8 Ad[3 * 1024];      // 48 KB [buf 3][k8 4][co 256]
    __shared__ short8 Bp[2 * 768];       // 24 KB [buf 2][ci8 4][dr 6][col 32]

    f32x4 acc[2][7];
    #pragma unroll
    for (int a = 0; a < 2; ++a)
        #pragma unroll
        for (int b = 0; b < 7; ++b) acc[a][b] = (f32x4){0.f, 0.f, 0.f, 0.f};

    int prb[7], cl0[7], hlog[7];
    #pragma unroll
    for (int b = 0; b < 7; ++b) {
        int p = b * 16 + ln;
        int hl = p / 28;
        hlog[b] = r0 + hl;
        prb[b] = hl * 32;
        cl0[b] = p % 28;
    }

    // B staging: 12 real insts + 4 dups (waves 6,7 dup inst 11)
    uint_t po[2];
    #pragma unroll
    for (int jj = 0; jj < 2; ++jj) {
        int i2 = min(wv * 2 + jj, 11);
        int f = i2 * 64 + lane;
        int ci8 = f / 192, rem = f % 192;
        int dr = rem >> 5, cl = rem & 31;
        po[jj] = (uint_t)((r0 + dr) * O1_ROW + cl * 256 + ci8 * 8);
    }
    // identity staging: 7 real insts + 1 dup (wave 7 dups inst 6)
    uint_t io;
    int islot;
    {
        islot = min(wv, 6);
        int f = islot * 64 + lane;
        int ci8 = f / 112, pos = f % 112;
        int h = r0 + pos / 28, w = pos % 28;
        io = (uint_t)(((2 * h + 1) * 57 + (2 * w + 1)) * 128 + ci8 * 8);
    }
    // A staging: 16 insts, 2/wave; inst i = wv*2+jj: k8 = i>>2, coq = i&3
    const ushort_t* asrc[2];
    int adst[2];
    #pragma unroll
    for (int jj = 0; jj < 2; ++jj) {
        int i = wv * 2 + jj;
        asrc[jj] = wT2 + (size_t)((i & 3) * 64 + lane) * 2432 + (i >> 2) * 8;
        adst[jj] = i * 1024;
    }

    const ushort_t* o1img = o1T + (size_t)n * O1_IMG;
    const ushort_t* xTimg = xT + (size_t)n * XT_IMG;

    auto stageA = [&](int k0, int buf) {           // 2 insts/wave = 16 KB total
        #pragma unroll
        for (int jj = 0; jj < 2; ++jj)
            gll16(asrc[jj] + k0, (char*)Ad + buf * 16384 + adst[jj]);
    };
    auto stageB = [&](int hb, int coff) {          // 2 insts/wave = 12 KB (+dups)
        #pragma unroll
        for (int jj = 0; jj < 2; ++jj)
            gll16(o1img + po[jj] + coff,
                  (char*)Bp + hb * 12288 + min(wv * 2 + jj, 11) * 1024);
    };
    auto stageI = [&](int ib, int idh) {           // 1 inst/wave = 7 KB (+dup)
        gll16(xTimg + io + idh * 32, (char*)Bp + ib * 12288 + islot * 1024);
    };

    // prologue: step 0's A and chunk 0's B, drained + published once
    stageB(0, 0);
    stageA(0, 0);
    WAITVM(0);
    BARRIER();

    for (int h = 0; h < 8; ++h) {
        #pragma unroll
        for (int t = 0; t < 9; ++t) {
            // A(s) lives in buf t%3 (9 = 0 mod 3); stage A(s+1) -> (t+1)%3
            if (t < 8)      stageA((t + 1) * 256 + h * 32, (t + 1) % 3);
            else if (h < 7) stageA((h + 1) * 32, 0);
            else            stageA(2304, 0);                 // -> identity step 0
            if (t == 1) {
                if (h < 7) { stageB((h + 1) & 1, (h + 1) * 32); WAITVM(4); }
                else       { stageI(0, 0);                      WAITVM(3); }
            } else if (t == 2) {
                if (h < 7) { WAITVM(4); } else { WAITVM(3); }
            } else {
                WAITVM(2);
            }
            BARRIER();
            const int ab = t % 3;
            const int kh = t / 3, kw = t - kh * 3;
            short8 af[2], bf[7];
            #pragma unroll
            for (int a = 0; a < 2; ++a)
                af[a] = Ad[ab * 1024 + quad * 256 + wv * 32 + a * 16 + ln];
            #pragma unroll
            for (int b = 0; b < 7; ++b)
                bf[b] = Bp[(h & 1) * 768 + quad * 192 + prb[b] + kh * 32 + cl0[b] + kw];
            __builtin_amdgcn_s_setprio(1);
            #pragma unroll
            for (int a = 0; a < 2; ++a)
                #pragma unroll
                for (int b = 0; b < 7; ++b)
                    acc[a][b] = __builtin_amdgcn_mfma_f32_16x16x32_bf16(
                        af[a], bf[b], acc[a][b], 0, 0, 0);
            __builtin_amdgcn_s_setprio(0);
        }
    }

    // identity: 4 steps of 32 ci. Drain own loads BEFORE the barrier (so it
    // publishes them); issue next A+I after the barrier (write-race-safe).
    #pragma unroll
    for (int idh = 0; idh < 4; ++idh) {
        WAITVM(0);
        BARRIER();
        if (idh < 3) {
            stageA(2304 + (idh + 1) * 32, (idh + 1) % 3);
            stageI((idh + 1) & 1, idh + 1);
        }
        short8 af[2], bf[7];
        #pragma unroll
        for (int a = 0; a < 2; ++a)
            af[a] = Ad[(idh % 3) * 1024 + quad * 256 + wv * 32 + a * 16 + ln];
        #pragma unroll
        for (int b = 0; b < 7; ++b)
            bf[b] = Bp[(idh & 1) * 768 + quad * 112 + b * 16 + ln];
        __builtin_amdgcn_s_setprio(1);
        #pragma unroll
        for (int a = 0; a < 2; ++a)
            #pragma unroll
            for (int b = 0; b < 7; ++b)
                acc[a][b] = __builtin_amdgcn_mfma_f32_16x16x32_bf16(
                    af[a], bf[b], acc[a][b], 0, 0, 0);
        __builtin_amdgcn_s_setprio(0);
    }

    // epilogue: hist overlaid on Ad; clamp -> f32 out (NCHW)
    __syncthreads();
    uint_t* hist = (uint_t*)Ad;
    for (int i = tid; i < NBINS; i += 512) hist[i] = 0;
    __syncthreads();

    #pragma unroll
    for (int a = 0; a < 2; ++a) {
        int co = wv * 32 + a * 16 + quad * 4;
        #pragma unroll
        for (int b = 0; b < 7; ++b) {
            #pragma unroll
            for (int r = 0; r < 4; ++r) {
                float v = acc[a][b][r];
                int bin = (int)((v - BIN_LO) * BIN_INV);
                bin = min(max(bin, 0), NBINS - 1);
                atomicAdd(&hist[bin], 1u);
                fout[((size_t)(n * 256 + co + r)) * SPATIAL +
                     hlog[b] * 28 + cl0[b]] = fminf(fmaxf(v, 0.f), 1.f);
            }
        }
    }

    __syncthreads();
    size_t blin = (size_t)bx * NBINS;
    for (int i = tid; i < NBINS; i += 512) bh[blin + i] = (ushort_t)hist[i];
}

// ---------------------------------------------------------------------------
// Reduce nblk per-block u16 histograms -> final u32 histogram
// ---------------------------------------------------------------------------
__global__ __launch_bounds__(256) void hreduce(
    const ushort_t* __restrict__ bh, uint_t* __restrict__ hf, int nblk)
{
    __shared__ uint_t p[256];
    int b0 = blockIdx.x * 64;
    int binl = threadIdx.x & 63, grp = threadIdx.x >> 6;
    uint_t s = 0;
    for (int j = grp; j < nblk; j += 4) s += bh[(size_t)j * NBINS + b0 + binl];
    p[threadIdx.x] = s;
    __syncthreads();
    if (threadIdx.x < 64)
        hf[b0 + threadIdx.x] = p[threadIdx.x] + p[64 + threadIdx.x] +
                               p[128 + threadIdx.x] + p[192 + threadIdx.x];
}

// ---------------------------------------------------------------------------
// Select 99 percentile values from the 2048-bin histogram
// ---------------------------------------------------------------------------
__global__ __launch_bounds__(1024) void select_k(
    const uint_t* __restrict__ hf, float* __restrict__ outp)
{
    __shared__ uint_t cs[1024];
    int t = threadIdx.x;
    uint_t s = hf[2 * t] + hf[2 * t + 1];
    cs[t] = s;
    __syncthreads();
    for (int d = 1; d < 1024; d <<= 1) {
        uint_t v = (t >= d) ? cs[t - d] : 0;
        __syncthreads();
        cs[t] += v;
        __syncthreads();
    }
    if (t >= 1 && t <= 99) {
        long long k = 1 + (long long)llrint(0.01 * (double)t * (double)(OUT_ELEMS - 1));
        int lo = 0, hi = 1023;
        while (lo < hi) { int mid = (lo + hi) >> 1; if ((long long)cs[mid] < k) lo = mid + 1; else hi = mid; }
        long long cum = (lo == 0) ? 0 : (long long)cs[lo - 1];
        int b = lo * 2;
        while (cum + (long long)hf[b] < k) { cum += hf[b]; ++b; }
        outp[t - 1] = BIN_LO + ((float)b + 0.5f) * BIN_W;
    }
}

// ---------------------------------------------------------------------------
extern "C" void kernel_launch(void* const* d_in, const int* in_sizes, int n_in,
                              void* d_out, int out_size, void* d_ws, size_t ws_size,
                              hipStream_t stream)
{
    const float* x   = (const float*)d_in[0];
    const float* w1  = (const float*)d_in[1];
    const float* w2  = (const float*)d_in[2];
    const float* wid = (const float*)d_in[3];
    float* out = (float*)d_out;

    char* ws = (char*)d_ws;
    ushort_t* xT  = (ushort_t*)ws;                         // 53,231,616 B (+4K pad)
    ushort_t* o1T = (ushort_t*)(ws + 53235712);            // 29,491,200 B (+4K pad)
    ushort_t* wT1 = (ushort_t*)(ws + 82731008);            //    589,824 B
    ushort_t* wT2 = (ushort_t*)(ws + 83320832);            //  1,245,184 B
    ushort_t* bhA = (ushort_t*)(ws + 84566016);            //  1,835,008 B (448 rows)
    ushort_t* bhB = (ushort_t*)(ws + 86401024);            //  2,097,152 B (448 used)
    uint_t*   hfA = (uint_t*)  (ws + 88498176);            //      8,192 B
    uint_t*   hfB = (uint_t*)  (ws + 88506368);            //      8,192 B

    zwtrans<<<dim3(125, 64), 256, 0, stream>>>((uint_t*)xT, (uint_t*)o1T,
                                               w1, w2, wid, wT1, wT2);
    xtrans<<<dim3(14, 64), 256, 0, stream>>>(x, xT);

    conv1_mfma<<<448, 512, 0, stream>>>(xT, wT1, o1T, bhA);
    conv2_mfma<<<448, 512, 0, stream>>>(o1T, xT, wT2, out, bhB);

    hreduce<<<32, 256, 0, stream>>>(bhA, hfA, 448);
    select_k<<<1, 1024, 0, stream>>>(hfA, out + OUT_ELEMS);
    hreduce<<<32, 256, 0, stream>>>(bhB, hfB, 448);
    select_k<<<1, 1024, 0, stream>>>(hfB, out + OUT_ELEMS + 99);
}

// Round 5
// 354.711 us; speedup vs baseline: 1.2159x; 1.2159x over previous
//
#include <hip/hip_runtime.h>

typedef unsigned short ushort_t;
typedef unsigned int uint_t;

using short8 = __attribute__((ext_vector_type(8))) short;
using f32x4  = __attribute__((ext_vector_type(4))) float;

#define N_BATCH   64
#define C_MID     256
#define H_OUT     28
#define W_OUT     28
#define SPATIAL   (H_OUT*W_OUT)
#define OUT_ELEMS (N_BATCH*C_MID*SPATIAL)   // 12,845,056

// histogram: 2048 bins over [-16,16), width 1/64
#define NBINS 2048
#define BIN_LO (-16.0f)
#define BIN_INV 64.0f
#define BIN_W  0.015625f

// padded channels-last geometry (u16 element units)
#define XT_ROW   (57*128)        // 7296
#define XT_IMG   (57*57*128)     // 415872
#define O1_ROW   (30*256)        // 7680
#define O1_IMG   (30*30*256)     // 230400

// counted waits + raw barrier (memory clobber pins LDS reads/writes ordering)
#define WAITVM(n) asm volatile("s_waitcnt vmcnt(" #n ")" ::: "memory")
#define BARRIER() asm volatile("s_barrier" ::: "memory")

__device__ __forceinline__ ushort_t f2bf(float f) {
    uint_t u = __float_as_uint(f);
    u += 0x7FFFu + ((u >> 16) & 1u);
    return (ushort_t)(u >> 16);
}

__device__ __forceinline__ void gll16(const ushort_t* g, void* l) {
    __builtin_amdgcn_global_load_lds(
        (const __attribute__((address_space(1))) unsigned int*)g,
        (__attribute__((address_space(3))) unsigned int*)l, 16, 0, 0);
}

// ---------------------------------------------------------------------------
// Merged: zero borders of xT/o1T + zero final histograms (blocks x<87) +
// weight transform (x>=87). hf zeroing added here (runs first each
// iteration, stream-ordered before hreduce's atomics).
// ---------------------------------------------------------------------------
__global__ __launch_bounds__(256) void zwtrans(
    uint_t* __restrict__ xT32, uint_t* __restrict__ o1T32,
    const float* __restrict__ w1, const float* __restrict__ w2,
    const float* __restrict__ wid, ushort_t* __restrict__ wT1,
    ushort_t* __restrict__ wT2, uint_t* __restrict__ hfA,
    uint_t* __restrict__ hfB)
{
    const int bxx = blockIdx.x, y = blockIdx.y, tid = threadIdx.x;
    if (bxx < 87) {
        int i = bxx * 256 + tid;
        int n = y;
        if (i >= 22080) return;
        if (i < 7232) {
            uint_t* base = xT32 + (size_t)n * (XT_IMG / 2);
            if (i < 3648) base[i] = 0;                              // row 0
            else { int j = i - 3648; int r = (j >> 6) + 1;          // col 0
                   base[r * (XT_ROW / 2) + (j & 63)] = 0; }
        } else {
            int k = i - 7232;
            uint_t* base = o1T32 + (size_t)n * (O1_IMG / 2);
            if (k < 3840) base[k] = 0;                              // row 0
            else if (k < 7680) base[29 * (O1_ROW / 2) + (k - 3840)] = 0;
            else if (k < 11264) { int j = k - 7680; int r = (j >> 7) + 1;
                   base[r * (O1_ROW / 2) + (j & 127)] = 0; }        // col 0
            else { int j = k - 11264; int r = (j >> 7) + 1;
                   base[r * (O1_ROW / 2) + 29 * 128 + (j & 127)] = 0; }
        }
    } else {
        int idx = ((bxx - 87) * 64 + y) * 256 + tid;   // 0..622591
        if (idx < 2048)      hfA[idx] = 0;
        else if (idx < 4096) hfB[idx - 2048] = 0;
        if (idx < 256 * 1152) {
            int co = idx / 1152, k = idx % 1152;
            int g = k >> 7, ci = k & 127;
            wT1[idx] = f2bf(w1[(co * 128 + ci) * 9 + g]);
        }
        if (idx < 256 * 2432) {
            int co = idx / 2432, k = idx % 2432;
            float v;
            if (k < 2304) { int g = k >> 8, ci = k & 255; v = w2[(co * 256 + ci) * 9 + g]; }
            else          { v = wid[co * 128 + (k - 2304)]; }
            wT2[idx] = f2bf(v);
        }
    }
}

// ---------------------------------------------------------------------------
// x transform: NCHW f32 -> padded channels-last bf16 xT[n][1+ih][1+iw][ci]
// ---------------------------------------------------------------------------
__global__ __launch_bounds__(256) void xtrans(
    const float* __restrict__ x, ushort_t* __restrict__ xT)
{
    __shared__ ushort_t t[224 * 130];
    const int tid = threadIdx.x;
    const int g = blockIdx.x, n = blockIdx.y;
    const float* xs = x + ((size_t)n * 128) * 3136 + g * 4 * 56;

    for (int it = 0; it < 112; ++it) {
        int f = it * 256 + tid;
        int ci = f / 224, rem = f % 224;
        t[rem * 130 + ci] = f2bf(xs[ci * 3136 + rem]);
    }
    __syncthreads();
    ushort_t* xo = xT + (size_t)n * XT_IMG + (g * 4 + 1) * XT_ROW + 128;
    for (int it = 0; it < 56; ++it) {
        int f = it * 256 + tid;
        int pos = f >> 6, c2 = f & 63;
        int r = pos / 56, iw = pos % 56;
        uint_t v = *(const uint_t*)&t[pos * 130 + c2 * 2];
        *(uint_t*)(xo + r * XT_ROW + iw * 128 + c2 * 2) = v;
    }
}

// ---------------------------------------------------------------------------
// conv1 (R1 version, best measured). A staging wave-private (counted vmcnt,
// no per-tap barrier); 2 barriers per ci-chunk for the shared B patch.
// ---------------------------------------------------------------------------
__global__ __launch_bounds__(256, 2) void conv1_mfma(
    const ushort_t* __restrict__ xT, const ushort_t* __restrict__ wT1,
    ushort_t* __restrict__ o1T, ushort_t* __restrict__ bh)
{
    const int bx = blockIdx.x;           // n*7 + rg
    const int tid = threadIdx.x;
    const int wv = tid >> 6, lane = tid & 63;
    const int ln = lane & 15, quad = lane >> 4;
    const int n = bx / 7, rg = bx % 7, r0 = rg * 4;

    __shared__ short8 Ald[2 * 1024];     // 32 KB  [buf][k8 4][co 256]
    __shared__ short8 Bp[2304];          // 36 KB  [k8 4][dr 9][j 57] (513/plane)

    f32x4 acc[4][7];
    #pragma unroll
    for (int a = 0; a < 4; ++a)
        #pragma unroll
        for (int b = 0; b < 7; ++b) acc[a][b] = (f32x4){0.f, 0.f, 0.f, 0.f};

    int drb[7], cl0[7];
    #pragma unroll
    for (int b = 0; b < 7; ++b) {
        int p = b * 16 + ln;
        drb[b] = 2 * (p / 28);           // + kh at use
        cl0[b] = p % 28;
    }

    uint_t poff[9];
    #pragma unroll
    for (int i = 0; i < 9; ++i) {
        int slot = (i * 4 + wv) * 64 + lane;
        int s2 = min(slot, 2051);
        int k8 = s2 / 513;
        int rem = s2 - k8 * 513;
        int dr = rem / 57, j = rem - dr * 57;
        int col = (j < 29) ? (2 * j) : (2 * (j - 29) + 1);
        poff[i] = (uint_t)((2 * r0 + dr) * XT_ROW + col * 128 + k8 * 8);
    }
    const uint_t aoff = (uint_t)((wv * 64 + lane) * 1152);

    const ushort_t* xTimg = xT + (size_t)n * XT_IMG;

    auto stageA = [&](int tap, int c, int buf) {
        #pragma unroll
        for (int jj = 0; jj < 4; ++jj)
            gll16(wT1 + aoff + jj * 8 + tap * 128 + c * 32,
                  (char*)Ald + buf * 16384 + (jj * 256 + wv * 64) * 16);
    };

    for (int c = 0; c < 4; ++c) {
        BARRIER();                       // all waves done reading Bp (prev chunk)
        #pragma unroll
        for (int i = 0; i < 9; ++i)
            gll16(xTimg + poff[i] + c * 32, (char*)Bp + ((i * 4 + wv) * 64) * 16);
        if (c == 0) stageA(0, 0, 0);
        WAITVM(0);                       // own B (+pending A) arrived
        BARRIER();                       // everyone's B arrived

        #pragma unroll
        for (int t = 0; t < 9; ++t) {
            const int st = c * 9 + t;
            const int buf = st & 1;
            if (t < 8)      stageA(t + 1, c, buf ^ 1);
            else if (c < 3) stageA(0, c + 1, buf ^ 1);
            if (c == 3 && t == 8) { WAITVM(0); } else { WAITVM(4); }
            const int kh = t / 3, kw = t - kh * 3;
            short8 af[4], bf[7];
            #pragma unroll
            for (int a = 0; a < 4; ++a)
                af[a] = Ald[buf * 1024 + quad * 256 + wv * 64 + a * 16 + ln];
            #pragma unroll
            for (int b = 0; b < 7; ++b) {
                int dr = drb[b] + kh;
                int j = (kw == 1) ? (29 + cl0[b]) : (cl0[b] + (kw >> 1));
                bf[b] = Bp[quad * 513 + dr * 57 + j];
            }
            __builtin_amdgcn_s_setprio(1);
            #pragma unroll
            for (int a = 0; a < 4; ++a)
                #pragma unroll
                for (int b = 0; b < 7; ++b)
                    acc[a][b] = __builtin_amdgcn_mfma_f32_16x16x32_bf16(
                        af[a], bf[b], acc[a][b], 0, 0, 0);
            __builtin_amdgcn_s_setprio(0);
        }
    }

    // epilogue: hist overlaid on Ald; clamp -> bf16 o1T (padded channels-last)
    __syncthreads();
    uint_t* hist = (uint_t*)Ald;
    for (int i = tid; i < NBINS; i += 256) hist[i] = 0;
    __syncthreads();

    ushort_t* oimg = o1T + (size_t)n * O1_IMG;
    #pragma unroll
    for (int a = 0; a < 4; ++a) {
        int co = wv * 64 + a * 16 + quad * 4;
        #pragma unroll
        for (int b = 0; b < 7; ++b) {
            int p = b * 16 + ln;
            int h = r0 + p / 28, w = p % 28;
            ushort_t pk[4];
            #pragma unroll
            for (int r = 0; r < 4; ++r) {
                float v = acc[a][b][r];
                int bin = (int)((v - BIN_LO) * BIN_INV);
                bin = min(max(bin, 0), NBINS - 1);
                atomicAdd(&hist[bin], 1u);
                pk[r] = f2bf(fminf(fmaxf(v, 0.f), 1.f));
            }
            uint2 u; u.x = (uint_t)pk[0] | ((uint_t)pk[1] << 16);
            u.y = (uint_t)pk[2] | ((uint_t)pk[3] << 16);
            *(uint2*)(oimg + ((h + 1) * 30 + (w + 1)) * 256 + co) = u;
        }
    }

    __syncthreads();
    size_t blin = (size_t)bx * NBINS;
    for (int i = tid; i < NBINS; i += 256) bh[blin + i] = (ushort_t)hist[i];
}

// ---------------------------------------------------------------------------
// conv2 + fused identity (R1 version, best measured: counted-vmcnt pipeline,
// A triple-buffered lead-1, B double-buffered 8-step lead, one barrier/step).
// ---------------------------------------------------------------------------
__global__ __launch_bounds__(256, 2) void conv2_mfma(
    const ushort_t* __restrict__ o1T, const ushort_t* __restrict__ xT,
    const ushort_t* __restrict__ wT2, float* __restrict__ fout,
    ushort_t* __restrict__ bh)
{
    const int bx = blockIdx.x;           // n*4 + rg
    const int by = blockIdx.y;
    const int tid = threadIdx.x;
    const int wv = tid >> 6, lane = tid & 63;
    const int ln = lane & 15, quad = lane >> 4;
    const int n = bx >> 2, rg = bx & 3, r0 = rg * 8;
    const int coh = wv & 1;
    const int pt  = wv >> 1;

    __shared__ short8 Ad[3 * 512];       // 24 KB [buf 3][k8 4][co 128]
    __shared__ short8 Bp[2 * 1280];      // 40 KB [buf 2][ci8 4][dr 10][col 32]

    f32x4 acc[4][7];
    #pragma unroll
    for (int a = 0; a < 4; ++a)
        #pragma unroll
        for (int b = 0; b < 7; ++b) acc[a][b] = (f32x4){0.f, 0.f, 0.f, 0.f};

    int prb[7], cl0[7], hlog[7];
    #pragma unroll
    for (int b = 0; b < 7; ++b) {
        int p = b * 16 + ln;
        int h = r0 + pt * 4 + p / 28;
        hlog[b] = h;
        prb[b] = (min(h, 27) - r0) * 32;
        cl0[b] = p % 28;
    }

    uint_t po[5];
    #pragma unroll
    for (int jj = 0; jj < 5; ++jj) {
        int f = (wv * 5 + jj) * 64 + lane;
        int ci8 = f / 320, rem = f % 320;
        int dr = rem >> 5, cl = rem & 31;
        po[jj] = (uint_t)(min(r0 + dr, 29) * O1_ROW + cl * 256 + ci8 * 8);
    }
    uint_t io[4];
    #pragma unroll
    for (int jj = 0; jj < 4; ++jj) {
        int i2 = min(wv * 4 + jj, 13);
        int slot = i2 * 64 + lane;
        int ci8 = slot / 224, pos = slot % 224;
        int h = min(r0 + pos / 28, 27), w = pos % 28;
        io[jj] = (uint_t)(((2 * h + 1) * 57 + (2 * w + 1)) * 128 + ci8 * 8);
    }

    const ushort_t* o1img = o1T + (size_t)n * O1_IMG;
    const ushort_t* xTimg = xT + (size_t)n * XT_IMG;
    const ushort_t* Ab0 = wT2 + (size_t)(by * 128 + lane) * 2432 + wv * 8;
    const ushort_t* Ab1 = Ab0 + (size_t)64 * 2432;

    auto stageA = [&](int k0, int buf) {           // 2 insts/wave = 8 KB total
        gll16(Ab0 + k0, (char*)Ad + buf * 8192 + wv * 2048);
        gll16(Ab1 + k0, (char*)Ad + buf * 8192 + wv * 2048 + 1024);
    };
    auto stageB = [&](int hb, int coff) {          // 5 insts/wave = 20 KB total
        #pragma unroll
        for (int jj = 0; jj < 5; ++jj)
            gll16(o1img + po[jj] + coff, (char*)Bp + hb * 20480 + (wv * 5 + jj) * 1024);
    };
    auto stageI = [&](int ib, int idh) {           // 4 insts/wave
        #pragma unroll
        for (int jj = 0; jj < 4; ++jj) {
            int i2 = min(wv * 4 + jj, 13);
            gll16(xTimg + io[jj] + idh * 32, (char*)Bp + ib * 20480 + i2 * 1024);
        }
    };

    // prologue: step 0's inputs (retired by step 0's WAITVM(2))
    stageB(0, 0);
    stageA(0, 0);

    for (int h = 0; h < 8; ++h) {
        #pragma unroll
        for (int t = 0; t < 9; ++t) {
            if (t < 8)      stageA((t + 1) * 256 + h * 32, (t + 1) % 3);
            else if (h < 7) stageA((h + 1) * 32, 0);
            else            stageA(2304, 0);                 // -> id step 72
            if (t == 1) {
                if (h < 7) { stageB((h + 1) & 1, (h + 1) * 32); WAITVM(7); }
                else       { stageI(0, 0);                      WAITVM(6); }
            } else {
                WAITVM(2);   // retire previous step's issues
            }
            BARRIER();
            const int abuf = t % 3;
            const int kh = t / 3, kw = t - kh * 3;
            short8 af[4], bf[7];
            #pragma unroll
            for (int a = 0; a < 4; ++a)
                af[a] = Ad[abuf * 512 + quad * 128 + coh * 64 + a * 16 + ln];
            #pragma unroll
            for (int b = 0; b < 7; ++b)
                bf[b] = Bp[(h & 1) * 1280 + quad * 320 + prb[b] + kh * 32 + cl0[b] + kw];
            __builtin_amdgcn_s_setprio(1);
            #pragma unroll
            for (int a = 0; a < 4; ++a)
                #pragma unroll
                for (int b = 0; b < 7; ++b)
                    acc[a][b] = __builtin_amdgcn_mfma_f32_16x16x32_bf16(
                        af[a], bf[b], acc[a][b], 0, 0, 0);
            __builtin_amdgcn_s_setprio(0);
        }
    }

    // identity: 4 steps of 32 ci
    #pragma unroll
    for (int idh = 0; idh < 4; ++idh) {
        if (idh < 3) { stageA(2304 + (idh + 1) * 32, (idh + 1) % 3); WAITVM(2); }
        else         { WAITVM(0); }
        BARRIER();
        if (idh < 3) stageI((idh + 1) & 1, idh + 1);
        short8 af[4], bf[7];
        #pragma unroll
        for (int a = 0; a < 4; ++a)
            af[a] = Ad[(idh % 3) * 512 + quad * 128 + coh * 64 + a * 16 + ln];
        #pragma unroll
        for (int b = 0; b < 7; ++b)
            bf[b] = Bp[(idh & 1) * 1280 + quad * 224 + pt * 112 + b * 16 + ln];
        __builtin_amdgcn_s_setprio(1);
        #pragma unroll
        for (int a = 0; a < 4; ++a)
            #pragma unroll
            for (int b = 0; b < 7; ++b)
                acc[a][b] = __builtin_amdgcn_mfma_f32_16x16x32_bf16(
                    af[a], bf[b], acc[a][b], 0, 0, 0);
        __builtin_amdgcn_s_setprio(0);
    }

    // epilogue: hist overlaid on Ad; clamp -> f32 out (NCHW)
    __syncthreads();
    uint_t* hist = (uint_t*)Ad;
    for (int i = tid; i < NBINS; i += 256) hist[i] = 0;
    __syncthreads();

    #pragma unroll
    for (int a = 0; a < 4; ++a) {
        int co = by * 128 + coh * 64 + a * 16 + quad * 4;
        #pragma unroll
        for (int b = 0; b < 7; ++b) {
            if (hlog[b] <= 27) {
                #pragma unroll
                for (int r = 0; r < 4; ++r) {
                    float v = acc[a][b][r];
                    int bin = (int)((v - BIN_LO) * BIN_INV);
                    bin = min(max(bin, 0), NBINS - 1);
                    atomicAdd(&hist[bin], 1u);
                    fout[((size_t)(n * 256 + co + r)) * SPATIAL +
                         hlog[b] * 28 + cl0[b]] = fminf(fmaxf(v, 0.f), 1.f);
                }
            }
        }
    }

    __syncthreads();
    size_t blin = (size_t)(by * 256 + bx) * NBINS;
    for (int i = tid; i < NBINS; i += 256) bh[blin + i] = (ushort_t)hist[i];
}

// ---------------------------------------------------------------------------
// Reduce per-block u16 histograms -> final u32 histograms. R5: 8x row-split
// with one device atomicAdd per bin per row-chunk (hf zeroed by zwtrans),
// both histograms in one launch (grid.z). 512 blocks vs old 32.
// ---------------------------------------------------------------------------
__global__ __launch_bounds__(256) void hreduce(
    const ushort_t* __restrict__ bhA, const ushort_t* __restrict__ bhB,
    uint_t* __restrict__ hfA, uint_t* __restrict__ hfB)
{
    const ushort_t* bh = blockIdx.z ? bhB : bhA;
    uint_t* hf = blockIdx.z ? hfB : hfA;
    const int nblk = blockIdx.z ? 512 : 448;
    __shared__ uint_t p[256];
    int b0 = blockIdx.x * 64;
    int binl = threadIdx.x & 63, grp = threadIdx.x >> 6;
    int rpb = (nblk + 7) / 8;                  // 56 or 64 rows per y-block
    int j0 = blockIdx.y * rpb;
    int j1 = min(j0 + rpb, nblk);
    uint_t s = 0;
    for (int j = j0 + grp; j < j1; j += 4) s += bh[(size_t)j * NBINS + b0 + binl];
    p[threadIdx.x] = s;
    __syncthreads();
    if (threadIdx.x < 64)
        atomicAdd(&hf[b0 + threadIdx.x],
                  p[threadIdx.x] + p[64 + threadIdx.x] +
                  p[128 + threadIdx.x] + p[192 + threadIdx.x]);
}

// ---------------------------------------------------------------------------
// Select 99 percentile values from each 2048-bin histogram (both in one
// launch: blockIdx.x picks histogram A/B).
// ---------------------------------------------------------------------------
__global__ __launch_bounds__(1024) void select_k(
    const uint_t* __restrict__ hfA, const uint_t* __restrict__ hfB,
    float* __restrict__ outp)
{
    const uint_t* hf = blockIdx.x ? hfB : hfA;
    float* op = outp + blockIdx.x * 99;
    __shared__ uint_t cs[1024];
    int t = threadIdx.x;
    uint_t s = hf[2 * t] + hf[2 * t + 1];
    cs[t] = s;
    __syncthreads();
    for (int d = 1; d < 1024; d <<= 1) {
        uint_t v = (t >= d) ? cs[t - d] : 0;
        __syncthreads();
        cs[t] += v;
        __syncthreads();
    }
    if (t >= 1 && t <= 99) {
        long long k = 1 + (long long)llrint(0.01 * (double)t * (double)(OUT_ELEMS - 1));
        int lo = 0, hi = 1023;
        while (lo < hi) { int mid = (lo + hi) >> 1; if ((long long)cs[mid] < k) lo = mid + 1; else hi = mid; }
        long long cum = (lo == 0) ? 0 : (long long)cs[lo - 1];
        int b = lo * 2;
        while (cum + (long long)hf[b] < k) { cum += hf[b]; ++b; }
        op[t - 1] = BIN_LO + ((float)b + 0.5f) * BIN_W;
    }
}

// ---------------------------------------------------------------------------
extern "C" void kernel_launch(void* const* d_in, const int* in_sizes, int n_in,
                              void* d_out, int out_size, void* d_ws, size_t ws_size,
                              hipStream_t stream)
{
    const float* x   = (const float*)d_in[0];
    const float* w1  = (const float*)d_in[1];
    const float* w2  = (const float*)d_in[2];
    const float* wid = (const float*)d_in[3];
    float* out = (float*)d_out;

    char* ws = (char*)d_ws;
    ushort_t* xT  = (ushort_t*)ws;                         // 53,231,616 B (+4K pad)
    ushort_t* o1T = (ushort_t*)(ws + 53235712);            // 29,491,200 B (+4K pad)
    ushort_t* wT1 = (ushort_t*)(ws + 82731008);            //    589,824 B
    ushort_t* wT2 = (ushort_t*)(ws + 83320832);            //  1,245,184 B
    ushort_t* bhA = (ushort_t*)(ws + 84566016);            //  1,835,008 B (448 rows)
    ushort_t* bhB = (ushort_t*)(ws + 86401024);            //  2,097,152 B (512 rows)
    uint_t*   hfA = (uint_t*)  (ws + 88498176);            //      8,192 B
    uint_t*   hfB = (uint_t*)  (ws + 88506368);            //      8,192 B

    zwtrans<<<dim3(125, 64), 256, 0, stream>>>((uint_t*)xT, (uint_t*)o1T,
                                               w1, w2, wid, wT1, wT2, hfA, hfB);
    xtrans<<<dim3(14, 64), 256, 0, stream>>>(x, xT);

    conv1_mfma<<<448, 256, 0, stream>>>(xT, wT1, o1T, bhA);
    conv2_mfma<<<dim3(256, 2), 256, 0, stream>>>(o1T, xT, wT2, out, bhB);

    hreduce<<<dim3(32, 8, 2), 256, 0, stream>>>(bhA, bhB, hfA, hfB);
    select_k<<<2, 1024, 0, stream>>>(hfA, hfB, out + OUT_ELEMS);
}